// Round 3
// baseline (281.316 us; speedup 1.0000x reference)
//
#include <hip/hip_runtime.h>
#include <math.h>

#define NROWS 32768
#define CDIM  512
#define G_    2
#define V_    320
#define NCOLS 640
#define DCODE 128

typedef short bf16x8 __attribute__((ext_vector_type(8)));
typedef float f32x16 __attribute__((ext_vector_type(16)));

__device__ __forceinline__ short f2bf(float f) {
    union { float f; unsigned u; } v; v.f = f;
    unsigned r = v.u + 0x7FFFu + ((v.u >> 16) & 1u);   // RTNE
    return (short)(r >> 16);
}

// W [512,640] f32 -> Wt [640,512] bf16
__global__ __launch_bounds__(256) void wprep(const float* __restrict__ w,
                                             short* __restrict__ wt) {
    int gid = blockIdx.x * 256 + threadIdx.x;
    int k = gid / NCOLS;
    int n = gid - k * NCOLS;
    wt[(size_t)n * CDIM + k] = f2bf(w[(size_t)k * NCOLS + n]);
}

// Block = 32 rows, 4 waves: wave = (ch<<1)|g. Wave tile: 32 rows x 160 cols.
// Grid 1024 -> 4 blocks/CU schedulable; acc only 80 regs/wave.
__global__ __launch_bounds__(256, 2) void gvq_main(
    const float* __restrict__ hidden,    // [32768,512] f32
    const float* __restrict__ gumbel_u,  // [65536,320] f32
    const short* __restrict__ wt,        // [640,512] bf16
    const float* __restrict__ bias,      // [640]
    const float* __restrict__ cv,        // [640,128]
    float* __restrict__ out,             // [32768,256] + perp scalar
    float* __restrict__ gavg)            // [640]
{
    __shared__ float s_pmax[G_][2][32];
    __shared__ float s_psum[G_][2][32];
    __shared__ float s_bestv[G_][2][32];
    __shared__ int   s_besti[G_][2][32];

    const int t    = threadIdx.x;
    const int wave = t >> 6;
    const int lane = t & 63;
    const int l31  = lane & 31;
    const int hw   = lane >> 5;
    const int g    = wave & 1;
    const int ch   = wave >> 1;
    const int m0   = blockIdx.x * 32;
    const int gcol0 = g * V_ + ch * 160;    // global wt row base for this wave

    f32x16 acc[5];
    #pragma unroll
    for (int tt = 0; tt < 5; ++tt)
        #pragma unroll
        for (int r = 0; r < 16; ++r) acc[tt][r] = 0.f;

    const float* hrow  = hidden + (size_t)(m0 + l31) * CDIM + hw * 8;
    const short* wbase = wt + (size_t)(gcol0 + l31) * CDIM + hw * 8;

    // ---- K loop: step 32, all 14 loads issued before MFMAs ----
    for (int k0 = 0; k0 < CDIM; k0 += 32) {
        float4 h0 = *(const float4*)(hrow + k0);
        float4 h1 = *(const float4*)(hrow + k0 + 4);
        float4 h2 = *(const float4*)(hrow + k0 + 16);
        float4 h3 = *(const float4*)(hrow + k0 + 20);
        bf16x8 b0[5], b1[5];
        #pragma unroll
        for (int tt = 0; tt < 5; ++tt) {
            const short* wp = wbase + (size_t)tt * 32 * CDIM + k0;
            b0[tt] = *(const bf16x8*)(wp);
            b1[tt] = *(const bf16x8*)(wp + 16);
        }
        bf16x8 a0, a1;
        a0[0]=f2bf(h0.x); a0[1]=f2bf(h0.y); a0[2]=f2bf(h0.z); a0[3]=f2bf(h0.w);
        a0[4]=f2bf(h1.x); a0[5]=f2bf(h1.y); a0[6]=f2bf(h1.z); a0[7]=f2bf(h1.w);
        a1[0]=f2bf(h2.x); a1[1]=f2bf(h2.y); a1[2]=f2bf(h2.z); a1[3]=f2bf(h2.w);
        a1[4]=f2bf(h3.x); a1[5]=f2bf(h3.y); a1[6]=f2bf(h3.z); a1[7]=f2bf(h3.w);
        #pragma unroll
        for (int tt = 0; tt < 5; ++tt)
            acc[tt] = __builtin_amdgcn_mfma_f32_32x32x16_bf16(a0, b0[tt], acc[tt], 0, 0, 0);
        #pragma unroll
        for (int tt = 0; tt < 5; ++tt)
            acc[tt] = __builtin_amdgcn_mfma_f32_32x32x16_bf16(a1, b1[tt], acc[tt], 0, 0, 0);
    }

    // ---- bias ----
    #pragma unroll
    for (int tt = 0; tt < 5; ++tt) {
        float bv = bias[gcol0 + tt * 32 + l31];
        #pragma unroll
        for (int r = 0; r < 16; ++r) acc[tt][r] += bv;
    }

    // ---- phase 1: per-wave partial row max over 160 cols ----
    // C/D layout: col = gcol0 + tt*32 + l31, row = (r&3)+8*(r>>2)+4*hw
    #pragma unroll
    for (int r = 0; r < 16; ++r) {
        float m = acc[0][r];
        #pragma unroll
        for (int tt = 1; tt < 5; ++tt) m = fmaxf(m, acc[tt][r]);
        #pragma unroll
        for (int o = 1; o <= 16; o <<= 1) m = fmaxf(m, __shfl_xor(m, o));
        const int row = (r & 3) + 8 * (r >> 2) + 4 * hw;
        if (l31 == r) s_pmax[g][ch][row] = m;
    }
    __syncthreads();

    // ---- phase 2: gumbel argmax + exp (overwrite acc) + partial sums ----
    #pragma unroll
    for (int r = 0; r < 16; ++r) {
        const int row = (r & 3) + 8 * (r >> 2) + 4 * hw;
        const float M = fmaxf(s_pmax[g][0][row], s_pmax[g][1][row]);
        const float* up = gumbel_u + ((size_t)(m0 + row) * G_ + g) * V_ + ch * 160;
        float best = -1e30f; int bi = 0;
        #pragma unroll
        for (int tt = 0; tt < 5; ++tt) {
            float z = acc[tt][r];
            float u = up[tt * 32 + l31];
            float gum = -__logf(-__logf(u + 1e-10f) + 1e-10f);
            float nv = z + gum;
            if (nv > best) { best = nv; bi = ch * 160 + tt * 32 + l31; }
            acc[tt][r] = __expf(z - M);
        }
        float s = acc[0][r] + acc[1][r] + acc[2][r] + acc[3][r] + acc[4][r];
        #pragma unroll
        for (int o = 1; o <= 16; o <<= 1) s += __shfl_xor(s, o);
        #pragma unroll
        for (int o = 1; o <= 16; o <<= 1) {
            float ov = __shfl_xor(best, o);
            int   oi = __shfl_xor(bi, o);
            if (ov > best || (ov == best && oi < bi)) { best = ov; bi = oi; }
        }
        if (l31 == r) {
            s_psum[g][ch][row]  = s;
            s_bestv[g][ch][row] = best;
            s_besti[g][ch][row] = bi;
        }
    }
    __syncthreads();

    // ---- phase 3a: probability accumulation -> global atomics ----
    float cp[5];
    #pragma unroll
    for (int tt = 0; tt < 5; ++tt) cp[tt] = 0.f;
    #pragma unroll
    for (int r = 0; r < 16; ++r) {
        const int row = (r & 3) + 8 * (r >> 2) + 4 * hw;
        const float inv = 1.f / (s_psum[g][0][row] + s_psum[g][1][row]);
        #pragma unroll
        for (int tt = 0; tt < 5; ++tt) cp[tt] += acc[tt][r] * inv;
    }
    #pragma unroll
    for (int tt = 0; tt < 5; ++tt)
        atomicAdd(&gavg[gcol0 + tt * 32 + l31], cp[tt]);

    // ---- phase 3b: final argmax + codevector gather + out write ----
    // wave (g,ch) writes rows ch*16 .. ch*16+15 of this block, 2 rows/iter
    #pragma unroll
    for (int i = 0; i < 8; ++i) {
        const int R = ch * 16 + i * 2 + hw;
        float v0 = s_bestv[g][0][R], v1 = s_bestv[g][1][R];
        int   i0 = s_besti[g][0][R], i1 = s_besti[g][1][R];
        int bidx = (v1 > v0) ? i1 : i0;   // tie -> ch0 (smaller index)
        float4 cvv = *(const float4*)(cv + ((size_t)g * V_ + bidx) * DCODE + l31 * 4);
        *(float4*)(out + (size_t)(m0 + R) * (G_ * DCODE) + g * DCODE + l31 * 4) = cvv;
    }
}

__global__ __launch_bounds__(64) void gvq_perp(const float* __restrict__ gavg,
                                               float* __restrict__ out)
{
    const int lane = threadIdx.x;
    float s0 = 0.f, s1 = 0.f;
    for (int v = lane; v < V_; v += 64) {
        float p0 = gavg[v]      * (1.f / NROWS);
        float p1 = gavg[V_ + v] * (1.f / NROWS);
        s0 += p0 * logf(p0 + 1e-7f);
        s1 += p1 * logf(p1 + 1e-7f);
    }
    #pragma unroll
    for (int o = 32; o >= 1; o >>= 1) {
        s0 += __shfl_xor(s0, o);
        s1 += __shfl_xor(s1, o);
    }
    if (lane == 0)
        out[(size_t)NROWS * (G_ * DCODE)] = expf(-s0) + expf(-s1);
}

extern "C" void kernel_launch(void* const* d_in, const int* in_sizes, int n_in,
                              void* d_out, int out_size, void* d_ws, size_t ws_size,
                              hipStream_t stream)
{
    const float* hidden = (const float*)d_in[0];
    const float* gu     = (const float*)d_in[1];
    const float* w      = (const float*)d_in[2];
    const float* b      = (const float*)d_in[3];
    const float* cv     = (const float*)d_in[4];
    float* out  = (float*)d_out;
    float* gavg = (float*)d_ws;                       // 640 f32
    short* wtb  = (short*)((char*)d_ws + 4096);       // 640*512 bf16 = 640KB

    hipMemsetAsync(d_ws, 0, NCOLS * sizeof(float), stream);
    wprep<<<(CDIM * NCOLS) / 256, 256, 0, stream>>>(w, wtb);
    gvq_main<<<NROWS / 32, 256, 0, stream>>>(hidden, gu, wtb, b, cv, out, gavg);
    gvq_perp<<<1, 64, 0, stream>>>(gavg, out);
}

// Round 4
// 185.676 us; speedup vs baseline: 1.5151x; 1.5151x over previous
//
#include <hip/hip_runtime.h>
#include <math.h>

#define NROWS 32768
#define CDIM  512
#define G_    2
#define V_    320
#define NCOLS 640
#define DCODE 128
#define BM    64
#define BK    32
#define NSLOT 32

typedef short bf16x8 __attribute__((ext_vector_type(8)));
typedef float f32x16 __attribute__((ext_vector_type(16)));

__device__ __forceinline__ short f2bf(float f) {
    union { float f; unsigned u; } v; v.f = f;
    unsigned r = v.u + 0x7FFFu + ((v.u >> 16) & 1u);   // RTNE
    return (short)(r >> 16);
}

__device__ __forceinline__ void gl_lds16(const void* g, void* l) {
    __builtin_amdgcn_global_load_lds(
        (const __attribute__((address_space(1))) unsigned int*)g,
        (__attribute__((address_space(3))) unsigned int*)l, 16, 0, 0);
}

// fused prep: hidden f32 -> hb bf16 (blocks 0..8191), W -> Wt bf16 (blocks 8192..9471)
__global__ __launch_bounds__(256) void prep(const float* __restrict__ hidden,
                                            const float* __restrict__ w,
                                            short* __restrict__ hb,
                                            short* __restrict__ wt)
{
    const int bid = blockIdx.x;
    if (bid < 8192) {
        int i = bid * 256 + threadIdx.x;              // 2,097,152 items of 8 f32
        const float4* src = (const float4*)hidden;
        float4 a = src[i * 2], b = src[i * 2 + 1];
        int4 o;
        o.x = (((int)(unsigned short)f2bf(a.y)) << 16) | (int)(unsigned short)f2bf(a.x);
        o.y = (((int)(unsigned short)f2bf(a.w)) << 16) | (int)(unsigned short)f2bf(a.z);
        o.z = (((int)(unsigned short)f2bf(b.y)) << 16) | (int)(unsigned short)f2bf(b.x);
        o.w = (((int)(unsigned short)f2bf(b.w)) << 16) | (int)(unsigned short)f2bf(b.z);
        ((int4*)hb)[i] = o;
    } else {
        int i = (bid - 8192) * 256 + threadIdx.x;     // 327,680
        int k = i / NCOLS, n = i - k * NCOLS;
        wt[(size_t)n * CDIM + k] = f2bf(w[(size_t)k * NCOLS + n]);
    }
}

// Block = 64 rows x one group (320 cols). 4 waves: wave = rh*2+ch,
// wave tile 32 rows x 160 cols, acc 5 x f32x16. LDS-staged double-buffered K-loop.
__global__ __launch_bounds__(256, 2) void gvq_gemm(
    const short* __restrict__ hb,        // [32768][512] bf16
    const float* __restrict__ gumbel_u,  // [65536][320] f32
    const short* __restrict__ wt,        // [640][512] bf16
    const float* __restrict__ bias,      // [640]
    const float* __restrict__ cv,        // [640][128]
    float* __restrict__ out,             // [32768][256] + perp scalar
    float* __restrict__ gavg)            // [NSLOT][640]
{
    // per buf: A[kc=4][row=64][8 bf16] = 2048 shorts, B[kc=4][n=320][8] = 10240 shorts
    __shared__ short lds[2][12288];
    __shared__ float s_pmax[2][BM];
    __shared__ float s_psum[2][BM];
    __shared__ float s_bestv[2][BM];
    __shared__ int   s_besti[2][BM];

    const int t    = threadIdx.x;
    const int wave = t >> 6;
    const int lane = t & 63;
    const int l31  = lane & 31;
    const int hw   = lane >> 5;
    const int rh   = wave >> 1;           // row half (rows rh*32..+32)
    const int ch   = wave & 1;            // col half (cols ch*160..+160)
    const int rb   = blockIdx.x;
    const int g    = blockIdx.y;
    const int m0   = rb * BM;

    // 24 stage-issues per K-tile, 6 per wave; wave-uniform LDS dest (lane*16 implicit)
    auto STAGE = [&](int buf, int kb) {
        short* base = &lds[buf][0];
        #pragma unroll
        for (int j = 0; j < 6; ++j) {
            const int id = wave + 4 * j;
            if (id < 4) {
                const int kc = id;
                gl_lds16(hb + (size_t)(m0 + lane) * CDIM + kb + kc * 8,
                         base + (size_t)kc * 64 * 8);
            } else {
                const int b = id - 4;
                const int kc = b / 5, nb = b - kc * 5;
                gl_lds16(wt + (size_t)(g * V_ + nb * 64 + lane) * CDIM + kb + kc * 8,
                         base + 2048 + ((size_t)kc * 320 + nb * 64) * 8);
            }
        }
    };

    f32x16 acc[5];
    #pragma unroll
    for (int tt = 0; tt < 5; ++tt)
        #pragma unroll
        for (int r = 0; r < 16; ++r) acc[tt][r] = 0.f;

    STAGE(0, 0);
    __syncthreads();

    for (int ts = 0; ts < 16; ++ts) {
        const int cur = ts & 1;
        if (ts < 15) STAGE(cur ^ 1, (ts + 1) * BK);
        const short* A  = &lds[cur][0];
        const short* Bp = &lds[cur][2048];
        #pragma unroll
        for (int kh = 0; kh < 2; ++kh) {
            const int kc = kh * 2 + hw;
            bf16x8 a = *(const bf16x8*)(A + (kc * 64 + rh * 32 + l31) * 8);
            bf16x8 bfr[5];
            #pragma unroll
            for (int tt = 0; tt < 5; ++tt)
                bfr[tt] = *(const bf16x8*)(Bp + (kc * 320 + ch * 160 + tt * 32 + l31) * 8);
            #pragma unroll
            for (int tt = 0; tt < 5; ++tt)
                acc[tt] = __builtin_amdgcn_mfma_f32_32x32x16_bf16(a, bfr[tt], acc[tt], 0, 0, 0);
        }
        __syncthreads();
    }

    // ---- bias ----  (C/D: col = g*320 + ch*160 + tt*32 + l31, row_local = rh*32+(r&3)+8*(r>>2)+4*hw)
    #pragma unroll
    for (int tt = 0; tt < 5; ++tt) {
        float bv = bias[g * V_ + ch * 160 + tt * 32 + l31];
        #pragma unroll
        for (int r = 0; r < 16; ++r) acc[tt][r] += bv;
    }

    // ---- phase 1: per-wave partial row max (160 cols) ----
    #pragma unroll
    for (int r = 0; r < 16; ++r) {
        float m = acc[0][r];
        #pragma unroll
        for (int tt = 1; tt < 5; ++tt) m = fmaxf(m, acc[tt][r]);
        #pragma unroll
        for (int o = 1; o <= 16; o <<= 1) m = fmaxf(m, __shfl_xor(m, o));
        const int rl = rh * 32 + (r & 3) + 8 * (r >> 2) + 4 * hw;
        if (l31 == r) s_pmax[ch][rl] = m;
    }
    __syncthreads();

    // ---- phase 2: gumbel argmax + exp (overwrite acc) + partial sums ----
    #pragma unroll
    for (int r = 0; r < 16; ++r) {
        const int rl = rh * 32 + (r & 3) + 8 * (r >> 2) + 4 * hw;
        const float M = fmaxf(s_pmax[0][rl], s_pmax[1][rl]);
        const float* up = gumbel_u + ((size_t)(m0 + rl) * G_ + g) * V_ + ch * 160;
        float best = -1e30f; int bi = 0;
        #pragma unroll
        for (int tt = 0; tt < 5; ++tt) {
            float z = acc[tt][r];
            float u = up[tt * 32 + l31];
            float gum = -__logf(-__logf(u + 1e-10f) + 1e-10f);
            float nv = z + gum;
            if (nv > best) { best = nv; bi = ch * 160 + tt * 32 + l31; }
            acc[tt][r] = __expf(z - M);
        }
        float s = acc[0][r] + acc[1][r] + acc[2][r] + acc[3][r] + acc[4][r];
        #pragma unroll
        for (int o = 1; o <= 16; o <<= 1) s += __shfl_xor(s, o);
        #pragma unroll
        for (int o = 1; o <= 16; o <<= 1) {
            float ov = __shfl_xor(best, o);
            int   oi = __shfl_xor(bi, o);
            if (ov > best || (ov == best && oi < bi)) { best = ov; bi = oi; }
        }
        if (l31 == r) {
            s_psum[ch][rl]  = s;
            s_bestv[ch][rl] = best;
            s_besti[ch][rl] = bi;
        }
    }
    __syncthreads();

    // ---- phase 3a: probability accumulation -> sliced global atomics ----
    float cp[5];
    #pragma unroll
    for (int tt = 0; tt < 5; ++tt) cp[tt] = 0.f;
    #pragma unroll
    for (int r = 0; r < 16; ++r) {
        const int rl = rh * 32 + (r & 3) + 8 * (r >> 2) + 4 * hw;
        const float inv = 1.f / (s_psum[0][rl] + s_psum[1][rl]);
        #pragma unroll
        for (int tt = 0; tt < 5; ++tt) cp[tt] += acc[tt][r] * inv;
    }
    float* gslot = gavg + (size_t)(rb & (NSLOT - 1)) * NCOLS;
    #pragma unroll
    for (int tt = 0; tt < 5; ++tt)
        atomicAdd(&gslot[g * V_ + ch * 160 + tt * 32 + l31], cp[tt]);

    // ---- phase 3b: final argmax + codevector gather + out write ----
    #pragma unroll
    for (int i = 0; i < 8; ++i) {
        const int R = wave * 16 + i * 2 + hw;
        float v0 = s_bestv[0][R], v1 = s_bestv[1][R];
        int   i0 = s_besti[0][R], i1 = s_besti[1][R];
        int bidx = (v1 > v0) ? i1 : i0;   // tie -> ch0 (smaller index)
        float4 cvv = *(const float4*)(cv + ((size_t)g * V_ + bidx) * DCODE + l31 * 4);
        *(float4*)(out + (size_t)(m0 + R) * (G_ * DCODE) + g * DCODE + l31 * 4) = cvv;
    }
}

__global__ __launch_bounds__(64) void gvq_perp(const float* __restrict__ gavg,
                                               float* __restrict__ out, int nslot)
{
    const int lane = threadIdx.x;
    float s0 = 0.f, s1 = 0.f;
    for (int v = lane; v < V_; v += 64) {
        float p0 = 0.f, p1 = 0.f;
        for (int s = 0; s < nslot; ++s) {
            p0 += gavg[(size_t)s * NCOLS + v];
            p1 += gavg[(size_t)s * NCOLS + V_ + v];
        }
        p0 *= (1.f / NROWS); p1 *= (1.f / NROWS);
        s0 += p0 * logf(p0 + 1e-7f);
        s1 += p1 * logf(p1 + 1e-7f);
    }
    #pragma unroll
    for (int o = 32; o >= 1; o >>= 1) {
        s0 += __shfl_xor(s0, o);
        s1 += __shfl_xor(s1, o);
    }
    if (lane == 0)
        out[(size_t)NROWS * (G_ * DCODE)] = expf(-s0) + expf(-s1);
}

// ---------------- fallback (R1, proven 245us) if ws too small ----------------
__global__ __launch_bounds__(256) void wprep_fb(const float* __restrict__ w,
                                                short* __restrict__ wt) {
    int gid = blockIdx.x * 256 + threadIdx.x;
    int k = gid / NCOLS;
    int n = gid - k * NCOLS;
    wt[(size_t)n * CDIM + k] = f2bf(w[(size_t)k * NCOLS + n]);
}

__global__ __launch_bounds__(256, 2) void gvq_main_fb(
    const float* __restrict__ hidden, const float* __restrict__ gumbel_u,
    const short* __restrict__ wt, const float* __restrict__ bias,
    const float* __restrict__ cv, float* __restrict__ out, float* __restrict__ gavg)
{
    __shared__ float savg[NCOLS];
    const int t = threadIdx.x;
    const int wave = t >> 6, lane = t & 63, l31 = lane & 31, hw = lane >> 5;
    const int g = wave & 1;
    const int m0 = blockIdx.x * 64 + (wave >> 1) * 32;
    for (int i = t; i < NCOLS; i += 256) savg[i] = 0.f;
    __syncthreads();
    f32x16 acc[10];
    #pragma unroll
    for (int tt = 0; tt < 10; ++tt)
        #pragma unroll
        for (int r = 0; r < 16; ++r) acc[tt][r] = 0.f;
    const float* hrow  = hidden + (size_t)(m0 + l31) * CDIM + hw * 8;
    const short* wbase = wt + (size_t)(g * V_ + l31) * CDIM + hw * 8;
    for (int k0 = 0; k0 < CDIM; k0 += 16) {
        float4 h0 = *(const float4*)(hrow + k0);
        float4 h1 = *(const float4*)(hrow + k0 + 4);
        bf16x8 a;
        a[0]=f2bf(h0.x); a[1]=f2bf(h0.y); a[2]=f2bf(h0.z); a[3]=f2bf(h0.w);
        a[4]=f2bf(h1.x); a[5]=f2bf(h1.y); a[6]=f2bf(h1.z); a[7]=f2bf(h1.w);
        bf16x8 b[10];
        #pragma unroll
        for (int tt = 0; tt < 10; ++tt)
            b[tt] = *(const bf16x8*)(wbase + (size_t)tt * 32 * CDIM + k0);
        #pragma unroll
        for (int tt = 0; tt < 10; ++tt)
            acc[tt] = __builtin_amdgcn_mfma_f32_32x32x16_bf16(a, b[tt], acc[tt], 0, 0, 0);
    }
    #pragma unroll
    for (int tt = 0; tt < 10; ++tt) {
        float bv = bias[g * V_ + tt * 32 + l31];
        #pragma unroll
        for (int r = 0; r < 16; ++r) acc[tt][r] += bv;
    }
    float mrow[16], inv[16];
    #pragma unroll
    for (int r = 0; r < 16; ++r) {
        float m = acc[0][r];
        #pragma unroll
        for (int tt = 1; tt < 10; ++tt) m = fmaxf(m, acc[tt][r]);
        #pragma unroll
        for (int o = 1; o <= 16; o <<= 1) m = fmaxf(m, __shfl_xor(m, o));
        mrow[r] = m;
        float ss = 0.f;
        #pragma unroll
        for (int tt = 0; tt < 10; ++tt) ss += __expf(acc[tt][r] - m);
        #pragma unroll
        for (int o = 1; o <= 16; o <<= 1) ss += __shfl_xor(ss, o);
        inv[r] = 1.f / ss;
    }
    float cp[10];
    #pragma unroll
    for (int tt = 0; tt < 10; ++tt) cp[tt] = 0.f;
    #pragma unroll
    for (int r = 0; r < 16; ++r) {
        const int R = (r & 3) + 8 * (r >> 2) + 4 * hw;
        const size_t nrow = (size_t)(m0 + R);
        const float* up = gumbel_u + (nrow * 2 + (size_t)g) * V_;
        float best = -1e30f; int bcol = 0;
        #pragma unroll
        for (int tt = 0; tt < 10; ++tt) {
            float z = acc[tt][r];
            cp[tt] += __expf(z - mrow[r]) * inv[r];
            float u = up[tt * 32 + l31];
            float gum = -__logf(-__logf(u + 1e-10f) + 1e-10f);
            float nv = z + gum;
            if (nv > best) { best = nv; bcol = tt * 32 + l31; }
        }
        #pragma unroll
        for (int o = 1; o <= 16; o <<= 1) {
            float ov = __shfl_xor(best, o);
            int   oc = __shfl_xor(bcol, o);
            if (ov > best || (ov == best && oc < bcol)) { best = ov; bcol = oc; }
        }
        float4 cvv = *(const float4*)(cv + ((size_t)g * V_ + bcol) * DCODE + l31 * 4);
        *(float4*)(out + nrow * (G_ * DCODE) + g * DCODE + l31 * 4) = cvv;
    }
    #pragma unroll
    for (int tt = 0; tt < 10; ++tt)
        atomicAdd(&savg[g * V_ + tt * 32 + l31], cp[tt]);
    __syncthreads();
    for (int i = t; i < NCOLS; i += 256) atomicAdd(&gavg[i], savg[i]);
}

extern "C" void kernel_launch(void* const* d_in, const int* in_sizes, int n_in,
                              void* d_out, int out_size, void* d_ws, size_t ws_size,
                              hipStream_t stream)
{
    const float* hidden = (const float*)d_in[0];
    const float* gu     = (const float*)d_in[1];
    const float* w      = (const float*)d_in[2];
    const float* b      = (const float*)d_in[3];
    const float* cv     = (const float*)d_in[4];
    float* out  = (float*)d_out;
    float* gavg = (float*)d_ws;

    const size_t NEED = 81920 + 655360 + (size_t)NROWS * CDIM * 2;  // 34,291,712 B
    if (ws_size >= NEED) {
        short* wtb = (short*)((char*)d_ws + 81920);
        short* hb  = (short*)((char*)d_ws + 81920 + 655360);
        hipMemsetAsync(d_ws, 0, NSLOT * NCOLS * sizeof(float), stream);
        prep<<<9472, 256, 0, stream>>>(hidden, w, hb, wtb);
        gvq_gemm<<<dim3(NROWS / BM, G_), 256, 0, stream>>>(hb, gu, wtb, b, cv, out, gavg);
        gvq_perp<<<1, 64, 0, stream>>>(gavg, out, NSLOT);
    } else {
        short* wtb = (short*)((char*)d_ws + 4096);
        hipMemsetAsync(d_ws, 0, NCOLS * sizeof(float), stream);
        wprep_fb<<<(CDIM * NCOLS) / 256, 256, 0, stream>>>(w, wtb);
        gvq_main_fb<<<NROWS / 64, 256, 0, stream>>>(hidden, gu, wtb, b, cv, out, gavg);
        gvq_perp<<<1, 64, 0, stream>>>(gavg, out, 1);
    }
}

// Round 5
// 172.011 us; speedup vs baseline: 1.6355x; 1.0794x over previous
//
#include <hip/hip_runtime.h>
#include <math.h>

#define NROWS 32768
#define CDIM  512
#define G_    2
#define V_    320
#define NCOLS 640
#define DCODE 128
#define BM    64
#define BK    32
#define NSLOT 32

typedef short bf16x8 __attribute__((ext_vector_type(8)));
typedef float f32x16 __attribute__((ext_vector_type(16)));

__device__ __forceinline__ short f2bf(float f) {
    union { float f; unsigned u; } v; v.f = f;
    unsigned r = v.u + 0x7FFFu + ((v.u >> 16) & 1u);   // RTNE
    return (short)(r >> 16);
}

__device__ __forceinline__ void gl_lds16(const void* g, void* l) {
    __builtin_amdgcn_global_load_lds(
        (const __attribute__((address_space(1))) unsigned int*)g,
        (__attribute__((address_space(3))) unsigned int*)l, 16, 0, 0);
}

// W [512,640] f32 -> Wt [640,512] bf16 (tiny: 1.3 MB)
__global__ __launch_bounds__(256) void wprep(const float* __restrict__ w,
                                             short* __restrict__ wt) {
    int gid = blockIdx.x * 256 + threadIdx.x;
    int k = gid / NCOLS;
    int n = gid - k * NCOLS;
    wt[(size_t)n * CDIM + k] = f2bf(w[(size_t)k * NCOLS + n]);
}

// Block = 64 rows x one group. 4 waves: wave = rh*2+ch, wave tile 32r x 160c.
// A: hidden f32 -> regs -> bf16 -> ds_write (fused convert). B: global_load_lds.
__global__ __launch_bounds__(256, 3) void gvq_gemm(
    const float* __restrict__ hidden,    // [32768][512] f32
    const float* __restrict__ gumbel_u,  // [65536][320] f32
    const short* __restrict__ wt,        // [640][512] bf16
    const float* __restrict__ bias,      // [640]
    const float* __restrict__ cv,        // [640][128]
    float* __restrict__ out,             // [32768][256] + perp scalar
    float* __restrict__ gavg)            // [NSLOT][640]
{
    __shared__ short ldsA[2][4][64][8];    // 8 KB
    __shared__ short ldsB[2][4][320][8];   // 40 KB
    __shared__ float s_psum[2][BM];
    __shared__ float s_bestv[2][BM];
    __shared__ int   s_besti[2][BM];

    const int t    = threadIdx.x;
    const int wave = t >> 6;
    const int lane = t & 63;
    const int l31  = lane & 31;
    const int hw   = lane >> 5;
    const int rh   = wave >> 1;
    const int ch   = wave & 1;
    const int rb   = blockIdx.x;
    const int g    = blockIdx.y;
    const int m0   = rb * BM;

    // A-staging mapping: thread -> (row, kc); 32B of k-range per thread per tile
    const int arow = t & 63, akc = t >> 6;
    const float* asrc = hidden + (size_t)(m0 + arow) * CDIM + akc * 8;

    f32x16 acc[5];
    #pragma unroll
    for (int tt = 0; tt < 5; ++tt)
        #pragma unroll
        for (int r = 0; r < 16; ++r) acc[tt][r] = 0.f;

    // ---- prologue: stage tile 0 ----
    {
        float4 h0 = *(const float4*)(asrc);
        float4 h1 = *(const float4*)(asrc + 4);
        #pragma unroll
        for (int j = 0; j < 5; ++j) {
            int id = wave * 5 + j, kc = id & 3, nb = id >> 2;
            gl_lds16(wt + (size_t)(g * V_ + nb * 64 + lane) * CDIM + kc * 8,
                     &ldsB[0][kc][nb * 64][0]);
        }
        bf16x8 p;
        p[0]=f2bf(h0.x); p[1]=f2bf(h0.y); p[2]=f2bf(h0.z); p[3]=f2bf(h0.w);
        p[4]=f2bf(h1.x); p[5]=f2bf(h1.y); p[6]=f2bf(h1.z); p[7]=f2bf(h1.w);
        *(bf16x8*)&ldsA[0][akc][arow][0] = p;
    }
    __syncthreads();

    // ---- K loop: 16 tiles, double-buffered, one barrier/tile ----
    for (int ts = 0; ts < 16; ++ts) {
        const int cur = ts & 1, nxt = cur ^ 1;
        float4 g0, g1;
        if (ts < 15) {
            const int kb = (ts + 1) * BK;
            g0 = *(const float4*)(asrc + kb);          // A loads first (oldest vmcnt)
            g1 = *(const float4*)(asrc + kb + 4);
            #pragma unroll
            for (int j = 0; j < 5; ++j) {
                int id = wave * 5 + j, kc = id & 3, nb = id >> 2;
                gl_lds16(wt + (size_t)(g * V_ + nb * 64 + lane) * CDIM + kb + kc * 8,
                         &ldsB[nxt][kc][nb * 64][0]);
            }
        }
        #pragma unroll
        for (int kh = 0; kh < 2; ++kh) {
            const int kc = kh * 2 + hw;
            bf16x8 a = *(const bf16x8*)&ldsA[cur][kc][rh * 32 + l31][0];
            bf16x8 bfr[5];
            #pragma unroll
            for (int tt = 0; tt < 5; ++tt)
                bfr[tt] = *(const bf16x8*)&ldsB[cur][kc][ch * 160 + tt * 32 + l31][0];
            #pragma unroll
            for (int tt = 0; tt < 5; ++tt)
                acc[tt] = __builtin_amdgcn_mfma_f32_32x32x16_bf16(a, bfr[tt], acc[tt], 0, 0, 0);
        }
        if (ts < 15) {
            bf16x8 p;
            p[0]=f2bf(g0.x); p[1]=f2bf(g0.y); p[2]=f2bf(g0.z); p[3]=f2bf(g0.w);
            p[4]=f2bf(g1.x); p[5]=f2bf(g1.y); p[6]=f2bf(g1.z); p[7]=f2bf(g1.w);
            *(bf16x8*)&ldsA[nxt][akc][arow][0] = p;
        }
        __syncthreads();
    }

    // ---- epilogue: exp(z) direct (no max pass), 1-log gumbel ratio argmax ----
    // C/D: col = g*320 + ch*160 + tt*32 + l31, local row = rh*32+(r&3)+8*(r>>2)+4*hw
    float bv[5];
    #pragma unroll
    for (int tt = 0; tt < 5; ++tt) bv[tt] = bias[g * V_ + ch * 160 + tt * 32 + l31];

    #pragma unroll
    for (int r = 0; r < 16; ++r) {
        const int rl = rh * 32 + (r & 3) + 8 * (r >> 2) + 4 * hw;
        const float* up = gumbel_u + ((size_t)(m0 + rl) * G_ + g) * V_ + ch * 160;
        float s = 0.f, best = -1e30f; int bi = 0;
        #pragma unroll
        for (int tt = 0; tt < 5; ++tt) {
            float z = fminf(acc[tt][r] + bv[tt], 60.f);
            float e = __expf(z);
            acc[tt][r] = e;                       // keep prob numerator for cp pass
            s += e;
            float u = up[tt * 32 + l31];
            float w = -__logf(u + 1e-10f) + 1e-10f;   // = -log(u+eps)+eps >= 0
            float ratio = e * __builtin_amdgcn_rcpf(w);  // argmax(z+gumbel) == argmax e/w
            if (ratio > best) { best = ratio; bi = ch * 160 + tt * 32 + l31; }
        }
        #pragma unroll
        for (int o = 1; o <= 16; o <<= 1) {
            s += __shfl_xor(s, o);
            float ov = __shfl_xor(best, o);
            int   oi = __shfl_xor(bi, o);
            if (ov > best || (ov == best && oi < bi)) { best = ov; bi = oi; }
        }
        if (l31 == r) {
            s_psum[ch][rl]  = s;
            s_bestv[ch][rl] = best;
            s_besti[ch][rl] = bi;
        }
    }
    __syncthreads();

    // ---- probability accumulation -> sliced global atomics ----
    float cp[5];
    #pragma unroll
    for (int tt = 0; tt < 5; ++tt) cp[tt] = 0.f;
    #pragma unroll
    for (int r = 0; r < 16; ++r) {
        const int rl = rh * 32 + (r & 3) + 8 * (r >> 2) + 4 * hw;
        const float inv = 1.f / (s_psum[0][rl] + s_psum[1][rl]);
        #pragma unroll
        for (int tt = 0; tt < 5; ++tt) cp[tt] += acc[tt][r] * inv;
    }
    float* gslot = gavg + (size_t)(rb & (NSLOT - 1)) * NCOLS;
    #pragma unroll
    for (int tt = 0; tt < 5; ++tt)
        atomicAdd(&gslot[g * V_ + ch * 160 + tt * 32 + l31], cp[tt]);

    // ---- final argmax across col-halves + codevector gather + write ----
    #pragma unroll
    for (int i = 0; i < 8; ++i) {
        const int R = wave * 16 + i * 2 + hw;
        float v0 = s_bestv[0][R], v1 = s_bestv[1][R];
        int   i0 = s_besti[0][R], i1 = s_besti[1][R];
        int bidx = (v1 > v0) ? i1 : i0;   // tie -> ch0 (smaller index)
        float4 cvv = *(const float4*)(cv + ((size_t)g * V_ + bidx) * DCODE + l31 * 4);
        *(float4*)(out + (size_t)(m0 + R) * (G_ * DCODE) + g * DCODE + l31 * 4) = cvv;
    }
}

__global__ __launch_bounds__(64) void gvq_perp(const float* __restrict__ gavg,
                                               float* __restrict__ out, int nslot)
{
    const int lane = threadIdx.x;
    float s0 = 0.f, s1 = 0.f;
    for (int v = lane; v < V_; v += 64) {
        float p0 = 0.f, p1 = 0.f;
        for (int s = 0; s < nslot; ++s) {
            p0 += gavg[(size_t)s * NCOLS + v];
            p1 += gavg[(size_t)s * NCOLS + V_ + v];
        }
        p0 *= (1.f / NROWS); p1 *= (1.f / NROWS);
        s0 += p0 * logf(p0 + 1e-7f);
        s1 += p1 * logf(p1 + 1e-7f);
    }
    #pragma unroll
    for (int o = 32; o >= 1; o >>= 1) {
        s0 += __shfl_xor(s0, o);
        s1 += __shfl_xor(s1, o);
    }
    if (lane == 0)
        out[(size_t)NROWS * (G_ * DCODE)] = expf(-s0) + expf(-s1);
}

extern "C" void kernel_launch(void* const* d_in, const int* in_sizes, int n_in,
                              void* d_out, int out_size, void* d_ws, size_t ws_size,
                              hipStream_t stream)
{
    const float* hidden = (const float*)d_in[0];
    const float* gu     = (const float*)d_in[1];
    const float* w      = (const float*)d_in[2];
    const float* b      = (const float*)d_in[3];
    const float* cv     = (const float*)d_in[4];
    float* out  = (float*)d_out;
    float* gavg = (float*)d_ws;                       // [NSLOT][640] f32 = 80 KB
    short* wtb  = (short*)((char*)d_ws + 81920);      // 640*512 bf16 = 640 KB

    hipMemsetAsync(d_ws, 0, NSLOT * NCOLS * sizeof(float), stream);
    wprep<<<(CDIM * NCOLS) / 256, 256, 0, stream>>>(w, wtb);
    gvq_gemm<<<dim3(NROWS / BM, G_), 256, 0, stream>>>(hidden, gu, wtb, b, cv, out, gavg);
    gvq_perp<<<1, 64, 0, stream>>>(gavg, out, NSLOT);
}

// Round 6
// 134.596 us; speedup vs baseline: 2.0901x; 1.2780x over previous
//
#include <hip/hip_runtime.h>
#include <math.h>

#define NROWS 32768
#define CDIM  512
#define G_    2
#define V_    320
#define NCOLS 640
#define DCODE 128
#define BM    64
#define BK    32
#define NSLOT 32

typedef short bf16x8 __attribute__((ext_vector_type(8)));
typedef float f32x4  __attribute__((ext_vector_type(4)));

__device__ __forceinline__ short f2bf(float f) {
    union { float f; unsigned u; } v; v.f = f;
    unsigned r = v.u + 0x7FFFu + ((v.u >> 16) & 1u);   // RTNE
    return (short)(r >> 16);
}

__device__ __forceinline__ void gl_lds16(const void* g, void* l) {
    __builtin_amdgcn_global_load_lds(
        (const __attribute__((address_space(1))) unsigned int*)g,
        (__attribute__((address_space(3))) unsigned int*)l, 16, 0, 0);
}

// W [512,640] f32 -> Wt [640,512] bf16 (1.3 MB -> 640 KB)
__global__ __launch_bounds__(256) void wprep(const float* __restrict__ w,
                                             short* __restrict__ wt) {
    int gid = blockIdx.x * 256 + threadIdx.x;
    int k = gid / NCOLS;
    int n = gid - k * NCOLS;
    wt[(size_t)n * CDIM + k] = f2bf(w[(size_t)k * NCOLS + n]);
}

// Block = 64 rows x one group (320 cols), 512 threads = 8 waves.
// wave = rq*2+ch: wave tile 16 rows x 160 cols, MFMA 16x16x32 bf16, acc = 10 x f32x4.
// A: hidden f32 -> regs (prefetch 2 tiles ahead) -> bf16 -> ds_write. B: global_load_lds.
__global__ __launch_bounds__(512, 4) void gvq_gemm(
    const float* __restrict__ hidden,    // [32768][512] f32
    const float* __restrict__ gumbel_u,  // [65536][320] f32
    const short* __restrict__ wt,        // [640][512] bf16
    const float* __restrict__ bias,      // [640]
    const float* __restrict__ cv,        // [640][128]
    float* __restrict__ out,             // [32768][256] + perp scalar
    float* __restrict__ gavg)            // [NSLOT][640]
{
    // kc-plane padded +2 rows: plane stride 1056/5152 B -> +8 bank shift per kq group
    __shared__ short ldsA[2][4][66][8];    // 8448 B
    __shared__ short ldsB[2][4][322][8];   // 41216 B
    __shared__ float s_psum[2][BM];
    __shared__ float s_bestv[2][BM];
    __shared__ int   s_besti[2][BM];

    const int t    = threadIdx.x;
    const int wave = t >> 6;
    const int lane = t & 63;
    const int l15  = lane & 15;
    const int kq   = lane >> 4;           // 0..3: k-chunk of 8 within K=32
    const int rq   = wave >> 1;           // 0..3: 16-row quarter
    const int ch   = wave & 1;            // 0..1: 160-col half
    const int rb   = blockIdx.x;
    const int g    = blockIdx.y;
    const int m0   = rb * BM;

    // A staging: threads 0..255, one bf16x8 row-chunk each
    const int arow = t & 63, akc = (t >> 6) & 3;
    const float* asrc = hidden + (size_t)(m0 + arow) * CDIM + akc * 8;

    f32x4 acc[10];
    #pragma unroll
    for (int tt = 0; tt < 10; ++tt)
        #pragma unroll
        for (int r = 0; r < 4; ++r) acc[tt][r] = 0.f;

    // ---- prologue: stage tile 0 directly; prefetch A-regs for tile 1 ----
    float4 ga0, ga1;                       // A regs for tile ts+1
    if (t < 256) {
        float4 h0 = *(const float4*)(asrc);
        float4 h1 = *(const float4*)(asrc + 4);
        bf16x8 p;
        p[0]=f2bf(h0.x); p[1]=f2bf(h0.y); p[2]=f2bf(h0.z); p[3]=f2bf(h0.w);
        p[4]=f2bf(h1.x); p[5]=f2bf(h1.y); p[6]=f2bf(h1.z); p[7]=f2bf(h1.w);
        *(bf16x8*)&ldsA[0][akc][arow][0] = p;
        ga0 = *(const float4*)(asrc + BK);
        ga1 = *(const float4*)(asrc + BK + 4);
    }
    for (int id = wave; id < 20; id += 8) {
        int kc = id & 3, nb = id >> 2;
        gl_lds16(wt + (size_t)(g * V_ + nb * 64 + lane) * CDIM + kc * 8,
                 &ldsB[0][kc][nb * 64][0]);
    }
    __syncthreads();

    // ---- K loop: 16 tiles of K=32, double-buffered LDS, A prefetched 2 ahead ----
    for (int ts = 0; ts < 16; ++ts) {
        const int cur = ts & 1, nxt = cur ^ 1;
        float4 gn0, gn1;
        if (ts < 14 && t < 256) {          // A-regs for tile ts+2
            const int kb = (ts + 2) * BK;
            gn0 = *(const float4*)(asrc + kb);
            gn1 = *(const float4*)(asrc + kb + 4);
        }
        if (ts < 15) {                     // B for tile ts+1
            const int kb = (ts + 1) * BK;
            for (int id = wave; id < 20; id += 8) {
                int kc = id & 3, nb = id >> 2;
                gl_lds16(wt + (size_t)(g * V_ + nb * 64 + lane) * CDIM + kb + kc * 8,
                         &ldsB[nxt][kc][nb * 64][0]);
            }
        }
        // compute tile ts
        bf16x8 a = *(const bf16x8*)&ldsA[cur][kq][rq * 16 + l15][0];
        #pragma unroll
        for (int tt = 0; tt < 10; ++tt) {
            bf16x8 b = *(const bf16x8*)&ldsB[cur][kq][ch * 160 + tt * 16 + l15][0];
            acc[tt] = __builtin_amdgcn_mfma_f32_16x16x32_bf16(a, b, acc[tt], 0, 0, 0);
        }
        if (ts < 15 && t < 256) {          // write A tile ts+1 (regs loaded 1 iter ago)
            bf16x8 p;
            p[0]=f2bf(ga0.x); p[1]=f2bf(ga0.y); p[2]=f2bf(ga0.z); p[3]=f2bf(ga0.w);
            p[4]=f2bf(ga1.x); p[5]=f2bf(ga1.y); p[6]=f2bf(ga1.z); p[7]=f2bf(ga1.w);
            *(bf16x8*)&ldsA[nxt][akc][arow][0] = p;
            ga0 = gn0; ga1 = gn1;
        }
        __syncthreads();
    }

    // ---- epilogue ----
    // C/D: col = g*320 + ch*160 + tt*16 + l15, local row rl = rq*16 + kq*4 + r
    float bvv[10];
    #pragma unroll
    for (int tt = 0; tt < 10; ++tt) bvv[tt] = bias[g * V_ + ch * 160 + tt * 16 + l15];

    {   // phase 1: exp(z) direct + row sums + 1-log gumbel ratio argmax, u-loads pipelined
        float ub[10], un[10];
        {
            const float* up0 = gumbel_u + ((size_t)(m0 + rq * 16 + kq * 4) * G_ + g) * V_ + ch * 160 + l15;
            #pragma unroll
            for (int tt = 0; tt < 10; ++tt) ub[tt] = up0[tt * 16];
        }
        #pragma unroll
        for (int r = 0; r < 4; ++r) {
            const int rl = rq * 16 + kq * 4 + r;
            if (r < 3) {
                const float* upn = gumbel_u + ((size_t)(m0 + rl + 1) * G_ + g) * V_ + ch * 160 + l15;
                #pragma unroll
                for (int tt = 0; tt < 10; ++tt) un[tt] = upn[tt * 16];
            }
            float s = 0.f, best = -1e30f; int bi = 0;
            #pragma unroll
            for (int tt = 0; tt < 10; ++tt) {
                float z = fminf(acc[tt][r] + bvv[tt], 60.f);
                float e = __expf(z);
                acc[tt][r] = e;                             // keep numerator for cp pass
                s += e;
                float w = -__logf(ub[tt] + 1e-10f) + 1e-10f;
                float ratio = e * __builtin_amdgcn_rcpf(w); // argmax(z+gumbel) == argmax e/w
                if (ratio > best) { best = ratio; bi = ch * 160 + tt * 16 + l15; }
            }
            #pragma unroll
            for (int o = 1; o <= 8; o <<= 1) {              // 16-lane group reduce
                s += __shfl_xor(s, o);
                float ov = __shfl_xor(best, o);
                int   oi = __shfl_xor(bi, o);
                if (ov > best || (ov == best && oi < bi)) { best = ov; bi = oi; }
            }
            if (l15 == 0) {
                s_psum[ch][rl]  = s;
                s_bestv[ch][rl] = best;
                s_besti[ch][rl] = bi;
            }
            #pragma unroll
            for (int tt = 0; tt < 10; ++tt) ub[tt] = un[tt];
        }
    }
    __syncthreads();

    // phase 2: probability accumulation -> fold kq groups -> sliced global atomics
    float cp[10];
    #pragma unroll
    for (int tt = 0; tt < 10; ++tt) cp[tt] = 0.f;
    #pragma unroll
    for (int r = 0; r < 4; ++r) {
        const int rl = rq * 16 + kq * 4 + r;
        const float inv = 1.f / (s_psum[0][rl] + s_psum[1][rl]);
        #pragma unroll
        for (int tt = 0; tt < 10; ++tt) cp[tt] += acc[tt][r] * inv;
    }
    #pragma unroll
    for (int tt = 0; tt < 10; ++tt) {
        cp[tt] += __shfl_xor(cp[tt], 16);
        cp[tt] += __shfl_xor(cp[tt], 32);
    }
    float* gslot = gavg + (size_t)(rb & (NSLOT - 1)) * NCOLS;
    if (kq == 0) {
        #pragma unroll
        for (int tt = 0; tt < 10; ++tt)
            atomicAdd(&gslot[g * V_ + ch * 160 + tt * 16 + l15], cp[tt]);
    }

    // phase 3: final argmax across col-halves + codevector gather + write
    #pragma unroll
    for (int i = 0; i < 8; ++i) {
        const int R = wave * 8 + i;
        float v0 = s_bestv[0][R], v1 = s_bestv[1][R];
        int   i0 = s_besti[0][R], i1 = s_besti[1][R];
        int bidx = (v1 > v0) ? i1 : i0;     // tie -> ch0 (smaller index)
        float2 cvv = *(const float2*)(cv + ((size_t)g * V_ + bidx) * DCODE + lane * 2);
        *(float2*)(out + (size_t)(m0 + R) * (G_ * DCODE) + g * DCODE + lane * 2) = cvv;
    }
}

__global__ __launch_bounds__(64) void gvq_perp(const float* __restrict__ gavg,
                                               float* __restrict__ out, int nslot)
{
    const int lane = threadIdx.x;
    float s0 = 0.f, s1 = 0.f;
    for (int v = lane; v < V_; v += 64) {
        float p0 = 0.f, p1 = 0.f;
        for (int s = 0; s < nslot; ++s) {
            p0 += gavg[(size_t)s * NCOLS + v];
            p1 += gavg[(size_t)s * NCOLS + V_ + v];
        }
        p0 *= (1.f / NROWS); p1 *= (1.f / NROWS);
        s0 += p0 * logf(p0 + 1e-7f);
        s1 += p1 * logf(p1 + 1e-7f);
    }
    #pragma unroll
    for (int o = 32; o >= 1; o >>= 1) {
        s0 += __shfl_xor(s0, o);
        s1 += __shfl_xor(s1, o);
    }
    if (lane == 0)
        out[(size_t)NROWS * (G_ * DCODE)] = expf(-s0) + expf(-s1);
}

extern "C" void kernel_launch(void* const* d_in, const int* in_sizes, int n_in,
                              void* d_out, int out_size, void* d_ws, size_t ws_size,
                              hipStream_t stream)
{
    const float* hidden = (const float*)d_in[0];
    const float* gu     = (const float*)d_in[1];
    const float* w      = (const float*)d_in[2];
    const float* b      = (const float*)d_in[3];
    const float* cv     = (const float*)d_in[4];
    float* out  = (float*)d_out;
    float* gavg = (float*)d_ws;                       // [NSLOT][640] f32 = 80 KB
    short* wtb  = (short*)((char*)d_ws + 81920);      // 640*512 bf16 = 640 KB

    hipMemsetAsync(d_ws, 0, NSLOT * NCOLS * sizeof(float), stream);
    wprep<<<(CDIM * NCOLS) / 256, 256, 0, stream>>>(w, wtb);
    gvq_gemm<<<dim3(NROWS / BM, G_), 512, 0, stream>>>(hidden, gu, wtb, b, cv, out, gavg);
    gvq_perp<<<1, 64, 0, stream>>>(gavg, out, NSLOT);
}